// Round 4
// baseline (446.752 us; speedup 1.0000x reference)
//
#include <hip/hip_runtime.h>

// QuantumLayer: h = x @ W + b  (B x 1024 @ 1024 x 2), row-normalize h,
// then a fixed 2-qubit circuit -> [B,2] <Z> values.
//
// R4 = CALIBRATION ROUND (intentionally slower). The kernel has been <160us
// in every round, below the rocprof top-5 cutoff, so its own counters were
// never visible; window arithmetic could not distinguish "kernel at 43us HBM
// floor" from "kernel at ~95us / 2.8 TB/s". This version keeps the R2
// structure but streams 3 extra dummy quadrants (offset q*B/4, wrapped)
// through the identical load+FMA pipeline, folded in via an opaque zero
// (asm) so nothing is DCE'd and the output is bit-identical. Total read
// ~1 GiB -> kernel >160us -> top dispatch, exposing FETCH_SIZE / hbm_gbps /
// VGPR_Count / OccupancyPercent / VALUBusy for the real structure.
// Decision: achieved BW >= ~6 TB/s -> revert to R2 & declare roofline;
//           <= ~4 TB/s -> counters name the limiter, fix it.

#define WAVES_PER_BLOCK 4
#define ROWS_PER_WAVE   8
#define ROWS_PER_BLOCK  (WAVES_PER_BLOCK * ROWS_PER_WAVE)

typedef float f4 __attribute__((ext_vector_type(4)));

__device__ __forceinline__ f4 ld_nt(const f4* p) {
    return __builtin_nontemporal_load(p);
}

__device__ __forceinline__ float2 run_circuit(float h0, float h1,
                                              const float cw[2][2],
                                              const float sw[2][2]) {
    float inv = rsqrtf(fmaxf(h0 * h0 + h1 * h1, 1e-12f));
    float s0, c0, s1, c1;
    __sincosf(0.5f * h0 * inv, &s0, &c0);
    __sincosf(0.5f * h1 * inv, &s1, &c1);

    float re[2][2], im[2][2];
    re[0][0] = c0 * c1;  im[0][0] = 0.0f;
    re[0][1] = 0.0f;     im[0][1] = -c0 * s1;
    re[1][0] = 0.0f;     im[1][0] = -s0 * c1;
    re[1][1] = -s0 * s1; im[1][1] = 0.0f;

#pragma unroll
    for (int l = 0; l < 2; ++l) {
        {
            float c = cw[l][0], s = sw[l][0];
#pragma unroll
            for (int k = 0; k < 2; ++k) {
                float ar = re[0][k], ai = im[0][k];
                float br = re[1][k], bi = im[1][k];
                re[0][k] = c * ar + s * bi;
                im[0][k] = c * ai - s * br;
                re[1][k] = s * ai + c * br;
                im[1][k] = c * bi - s * ar;
            }
        }
        {
            float c = cw[l][1], s = sw[l][1];
#pragma unroll
            for (int k = 0; k < 2; ++k) {
                float ar = re[k][0], ai = im[k][0];
                float br = re[k][1], bi = im[k][1];
                re[k][0] = c * ar + s * bi;
                im[k][0] = c * ai - s * br;
                re[k][1] = s * ai + c * br;
                im[k][1] = c * bi - s * ar;
            }
        }
        {
            float tr = re[1][0], ti = im[1][0];
            re[1][0] = re[1][1]; im[1][0] = im[1][1];
            re[1][1] = tr;       im[1][1] = ti;
        }
    }

    float p00 = re[0][0] * re[0][0] + im[0][0] * im[0][0];
    float p01 = re[0][1] * re[0][1] + im[0][1] * im[0][1];
    float p10 = re[1][0] * re[1][0] + im[1][0] * im[1][0];
    float p11 = re[1][1] * re[1][1] + im[1][1] * im[1][1];

    float2 z;
    z.x = (p00 + p01) - (p10 + p11);
    z.y = (p00 + p10) - (p01 + p11);
    return z;
}

#define PAIR_FMA(pa, pb, d0, d1, d2, d3)                                   \
    do {                                                                   \
        _Pragma("unroll")                                                  \
        for (int j = 0; j < 4; ++j) {                                      \
            f4 vA = pa[j];                                                 \
            f4 vB = pb[j];                                                 \
            d0 = fmaf(vA.x, wA[j].x, d0); d1 = fmaf(vA.x, wA[j].y, d1);    \
            d0 = fmaf(vA.y, wA[j].z, d0); d1 = fmaf(vA.y, wA[j].w, d1);    \
            d0 = fmaf(vA.z, wB[j].x, d0); d1 = fmaf(vA.z, wB[j].y, d1);    \
            d0 = fmaf(vA.w, wB[j].z, d0); d1 = fmaf(vA.w, wB[j].w, d1);    \
            d2 = fmaf(vB.x, wA[j].x, d2); d3 = fmaf(vB.x, wA[j].y, d3);    \
            d2 = fmaf(vB.y, wA[j].z, d2); d3 = fmaf(vB.y, wA[j].w, d3);    \
            d2 = fmaf(vB.z, wB[j].x, d2); d3 = fmaf(vB.z, wB[j].y, d3);    \
            d2 = fmaf(vB.w, wB[j].z, d2); d3 = fmaf(vB.w, wB[j].w, d3);    \
        }                                                                  \
    } while (0)

#define PAIR_LOAD(pa, pb, row)                                             \
    do {                                                                   \
        const f4* __restrict__ xp = x4 + (size_t)(row) * 256;              \
        _Pragma("unroll")                                                  \
        for (int j = 0; j < 4; ++j) {                                      \
            const int f = lane + 64 * j;                                   \
            pa[j] = ld_nt(xp + f);                                         \
            pb[j] = ld_nt(xp + 256 + f);                                   \
        }                                                                  \
    } while (0)

__global__ __launch_bounds__(256) void qlayer_kernel(
    const float* __restrict__ x,    // [B,1024]
    const float* __restrict__ w,    // [1024,2] row-major: w[d*2+q]
    const float* __restrict__ bias, // [2]
    const float* __restrict__ wq,   // [2,2]
    float* __restrict__ out,        // [B,2]
    int B)
{
    const int lane = threadIdx.x & 63;
    const int wave = threadIdx.x >> 6;
    const int rowBase = (blockIdx.x * WAVES_PER_BLOCK + wave) * ROWS_PER_WAVE;
    if (rowBase >= B) return;

    const f4* __restrict__ w4 = (const f4*)w;
    f4 wA[4], wB[4];
#pragma unroll
    for (int j = 0; j < 4; ++j) {
        int f = lane + 64 * j;
        wA[j] = w4[2 * f];
        wB[j] = w4[2 * f + 1];
    }

    const float b0 = bias[0], b1 = bias[1];

    float cw[2][2], sw[2][2];
#pragma unroll
    for (int l = 0; l < 2; ++l) {
#pragma unroll
        for (int q = 0; q < 2; ++q) {
            float t = 0.5f * wq[l * 2 + q];
            __sincosf(t, &sw[l][q], &cw[l][q]);
        }
    }

    float2* __restrict__ out2 = (float2*)out;
    const f4* __restrict__ x4 = (const f4*)x;

    if (rowBase + ROWS_PER_WAVE <= B) {
        f4 Xa[4], Xb[4], Ya[4], Yb[4];

        // Opaque zero: compiler cannot fold/DCE the dummy pipeline through it.
        float zk;
        asm volatile("v_mov_b32 %0, 0" : "=v"(zk));

        // ---- dummy quadrants (calibration traffic, 3 x 32 KB per wave) ----
        float d0 = 0.f, d1 = 0.f, d2 = 0.f, d3 = 0.f;
        float d4 = 0.f, d5 = 0.f, d6 = 0.f, d7 = 0.f;
        if ((B & 31) == 0) {
            const int qstep = B >> 2;   // multiple of 8 when B%32==0
#pragma unroll
            for (int q = 1; q < 4; ++q) {
                int db = rowBase + q * qstep;
                if (db >= B) db -= B;
                PAIR_LOAD(Xa, Xb, db + 0);
                PAIR_LOAD(Ya, Yb, db + 2);
                PAIR_FMA(Xa, Xb, d0, d1, d2, d3);
                PAIR_LOAD(Xa, Xb, db + 4);
                PAIR_FMA(Ya, Yb, d4, d5, d6, d7);
                PAIR_LOAD(Ya, Yb, db + 6);
                PAIR_FMA(Xa, Xb, d0, d1, d2, d3);
                PAIR_FMA(Ya, Yb, d4, d5, d6, d7);
            }
        }

        // ---- real work: identical to R2 fast path ----
        PAIR_LOAD(Xa, Xb, rowBase + 0);   // P0
        PAIR_LOAD(Ya, Yb, rowBase + 2);   // P1

        // ---- group 0: rows rowBase..rowBase+3 ----
        {
            float s0 = 0.f, s1 = 0.f, s2 = 0.f, s3 = 0.f;
            float s4 = 0.f, s5 = 0.f, s6 = 0.f, s7 = 0.f;

            PAIR_FMA(Xa, Xb, s0, s1, s2, s3);   // consumes P0
            PAIR_LOAD(Xa, Xb, rowBase + 4);     // issue P2
            PAIR_FMA(Ya, Yb, s4, s5, s6, s7);   // consumes P1
            PAIR_LOAD(Ya, Yb, rowBase + 6);     // issue P3

            // fold dummy sums through opaque zero (exact no-op on values)
            s0 = fmaf(d0, zk, s0); s1 = fmaf(d1, zk, s1);
            s2 = fmaf(d2, zk, s2); s3 = fmaf(d3, zk, s3);
            s4 = fmaf(d4, zk, s4); s5 = fmaf(d5, zk, s5);
            s6 = fmaf(d6, zk, s6); s7 = fmaf(d7, zk, s7);

#pragma unroll
            for (int off = 32; off >= 1; off >>= 1) {
                s0 += __shfl_xor(s0, off, 64);
                s1 += __shfl_xor(s1, off, 64);
                s2 += __shfl_xor(s2, off, 64);
                s3 += __shfl_xor(s3, off, 64);
                s4 += __shfl_xor(s4, off, 64);
                s5 += __shfl_xor(s5, off, 64);
                s6 += __shfl_xor(s6, off, 64);
                s7 += __shfl_xor(s7, off, 64);
            }

            const int k = lane & 3;
            float h0 = (k & 1) ? s2 : s0;
            float h0h = (k & 1) ? s6 : s4;
            h0 = (k & 2) ? h0h : h0;
            float h1 = (k & 1) ? s3 : s1;
            float h1h = (k & 1) ? s7 : s5;
            h1 = (k & 2) ? h1h : h1;

            float2 z = run_circuit(h0 + b0, h1 + b1, cw, sw);
            if (lane < 4) out2[rowBase + lane] = z;
        }

        // ---- group 1: rows rowBase+4..rowBase+7 ----
        {
            float s0 = 0.f, s1 = 0.f, s2 = 0.f, s3 = 0.f;
            float s4 = 0.f, s5 = 0.f, s6 = 0.f, s7 = 0.f;

            PAIR_FMA(Xa, Xb, s0, s1, s2, s3);   // consumes P2
            PAIR_FMA(Ya, Yb, s4, s5, s6, s7);   // consumes P3

#pragma unroll
            for (int off = 32; off >= 1; off >>= 1) {
                s0 += __shfl_xor(s0, off, 64);
                s1 += __shfl_xor(s1, off, 64);
                s2 += __shfl_xor(s2, off, 64);
                s3 += __shfl_xor(s3, off, 64);
                s4 += __shfl_xor(s4, off, 64);
                s5 += __shfl_xor(s5, off, 64);
                s6 += __shfl_xor(s6, off, 64);
                s7 += __shfl_xor(s7, off, 64);
            }

            const int k = lane & 3;
            float h0 = (k & 1) ? s2 : s0;
            float h0h = (k & 1) ? s6 : s4;
            h0 = (k & 2) ? h0h : h0;
            float h1 = (k & 1) ? s3 : s1;
            float h1h = (k & 1) ? s7 : s5;
            h1 = (k & 2) ? h1h : h1;

            float2 z = run_circuit(h0 + b0, h1 + b1, cw, sw);
            if (lane < 4) out2[rowBase + 4 + lane] = z;
        }
    } else {
        // ---- tail path: guarded, non-pipelined ----
#pragma unroll
        for (int r = 0; r < ROWS_PER_WAVE; r += 2) {
            const int rowA = rowBase + r;
            if (rowA >= B) break;
            const int rowB = rowA + 1;
            const bool hasB = (rowB < B);

            const f4* __restrict__ xA = x4 + (size_t)rowA * 256;
            const f4* __restrict__ xB = x4 + (size_t)(hasB ? rowB : rowA) * 256;

            float a0 = 0.f, a1 = 0.f, c0s = 0.f, c1s = 0.f;
#pragma unroll
            for (int j = 0; j < 4; ++j) {
                const int f = lane + 64 * j;
                f4 vA = xA[f];
                f4 vB = xB[f];
                a0 = fmaf(vA.x, wA[j].x, a0); a1 = fmaf(vA.x, wA[j].y, a1);
                a0 = fmaf(vA.y, wA[j].z, a0); a1 = fmaf(vA.y, wA[j].w, a1);
                a0 = fmaf(vA.z, wB[j].x, a0); a1 = fmaf(vA.z, wB[j].y, a1);
                a0 = fmaf(vA.w, wB[j].z, a0); a1 = fmaf(vA.w, wB[j].w, a1);
                c0s = fmaf(vB.x, wA[j].x, c0s); c1s = fmaf(vB.x, wA[j].y, c1s);
                c0s = fmaf(vB.y, wA[j].z, c0s); c1s = fmaf(vB.y, wA[j].w, c1s);
                c0s = fmaf(vB.z, wB[j].x, c0s); c1s = fmaf(vB.z, wB[j].y, c1s);
                c0s = fmaf(vB.w, wB[j].z, c0s); c1s = fmaf(vB.w, wB[j].w, c1s);
            }

#pragma unroll
            for (int off = 32; off >= 1; off >>= 1) {
                a0  += __shfl_xor(a0, off, 64);
                a1  += __shfl_xor(a1, off, 64);
                c0s += __shfl_xor(c0s, off, 64);
                c1s += __shfl_xor(c1s, off, 64);
            }

            float2 zA = run_circuit(a0 + b0, a1 + b1, cw, sw);
            float2 zB = run_circuit(c0s + b0, c1s + b1, cw, sw);

            if (lane == 0) {
                out2[rowA] = zA;
                if (hasB) out2[rowB] = zB;
            }
        }
    }
}

extern "C" void kernel_launch(void* const* d_in, const int* in_sizes, int n_in,
                              void* d_out, int out_size, void* d_ws, size_t ws_size,
                              hipStream_t stream) {
    const float* x    = (const float*)d_in[0];
    const float* w    = (const float*)d_in[1];
    const float* bias = (const float*)d_in[2];
    const float* wq   = (const float*)d_in[3];
    float* out = (float*)d_out;

    const int B = in_sizes[0] / 1024;
    const int grid = (B + ROWS_PER_BLOCK - 1) / ROWS_PER_BLOCK;
    qlayer_kernel<<<grid, 256, 0, stream>>>(x, w, bias, wq, out, B);
}

// Round 5
// 333.162 us; speedup vs baseline: 1.3409x; 1.3409x over previous
//
#include <hip/hip_runtime.h>

// QuantumLayer: h = x @ W + b  (B x 1024 @ 1024 x 2), row-normalize h,
// then a fixed 2-qubit circuit -> [B,2] <Z> values.
//
// R5 = revert to proven-best R2 structure after R4 calibration.
// R4's 4x-traffic calibration measured the load pipeline at 6.55 TB/s
// effective (1 GiB in 164 us, VGPR=88), i.e. the 1x kernel runs at
// ~42 us = 256 MiB / 6.5 TB/s = the HBM-read floor (ideal 42.6 us at the
// 6.3 TB/s achievable ceiling). The remaining ~293 us of the timed window
// is harness poison-fill/restore traffic (1 GiB fill ~162 us + restore),
// invariant to kernel changes. This kernel is at the memory roofline.
//
// Structure: one wave per 8 rows; lane-level float4 loads (16B/lane,
// fully coalesced, nontemporal); depth-2 ring prefetch (16 loads in
// flight through each reduce tail); batched 8-sum butterfly reduce;
// one circuit evaluation covers 4 rows via lane-select (sums are
// lane-uniform post-butterfly).

#define WAVES_PER_BLOCK 4
#define ROWS_PER_WAVE   8
#define ROWS_PER_BLOCK  (WAVES_PER_BLOCK * ROWS_PER_WAVE)

typedef float f4 __attribute__((ext_vector_type(4)));

__device__ __forceinline__ f4 ld_nt(const f4* p) {
    return __builtin_nontemporal_load(p);
}

__device__ __forceinline__ float2 run_circuit(float h0, float h1,
                                              const float cw[2][2],
                                              const float sw[2][2]) {
    // normalize (h0,h1) to unit norm, angles theta/2
    float inv = rsqrtf(fmaxf(h0 * h0 + h1 * h1, 1e-12f));
    float s0, c0, s1, c1;
    __sincosf(0.5f * h0 * inv, &s0, &c0);
    __sincosf(0.5f * h1 * inv, &s1, &c1);

    // State after RX(h0) wire0, RX(h1) wire1 applied to |00>, hand-expanded:
    // s00 = c0*c1 ; s01 = -i*c0*s1 ; s10 = -i*s0*c1 ; s11 = -s0*s1
    float re[2][2], im[2][2];
    re[0][0] = c0 * c1;  im[0][0] = 0.0f;
    re[0][1] = 0.0f;     im[0][1] = -c0 * s1;
    re[1][0] = 0.0f;     im[1][0] = -s0 * c1;
    re[1][1] = -s0 * s1; im[1][1] = 0.0f;

#pragma unroll
    for (int l = 0; l < 2; ++l) {
        // RX on wire 0 (first index)
        {
            float c = cw[l][0], s = sw[l][0];
#pragma unroll
            for (int k = 0; k < 2; ++k) {
                float ar = re[0][k], ai = im[0][k];
                float br = re[1][k], bi = im[1][k];
                re[0][k] = c * ar + s * bi;
                im[0][k] = c * ai - s * br;
                re[1][k] = s * ai + c * br;
                im[1][k] = c * bi - s * ar;
            }
        }
        // RX on wire 1 (second index)
        {
            float c = cw[l][1], s = sw[l][1];
#pragma unroll
            for (int k = 0; k < 2; ++k) {
                float ar = re[k][0], ai = im[k][0];
                float br = re[k][1], bi = im[k][1];
                re[k][0] = c * ar + s * bi;
                im[k][0] = c * ai - s * br;
                re[k][1] = s * ai + c * br;
                im[k][1] = c * bi - s * ar;
            }
        }
        // CNOT(0 -> 1): swap s10 <-> s11
        {
            float tr = re[1][0], ti = im[1][0];
            re[1][0] = re[1][1]; im[1][0] = im[1][1];
            re[1][1] = tr;       im[1][1] = ti;
        }
    }

    float p00 = re[0][0] * re[0][0] + im[0][0] * im[0][0];
    float p01 = re[0][1] * re[0][1] + im[0][1] * im[0][1];
    float p10 = re[1][0] * re[1][0] + im[1][0] * im[1][0];
    float p11 = re[1][1] * re[1][1] + im[1][1] * im[1][1];

    float2 z;
    z.x = (p00 + p01) - (p10 + p11);
    z.y = (p00 + p10) - (p01 + p11);
    return z;
}

// FMA a loaded pair (rows A=pa[], B=pb[]) against weight frags -> 4 sums.
#define PAIR_FMA(pa, pb, d0, d1, d2, d3)                                   \
    do {                                                                   \
        _Pragma("unroll")                                                  \
        for (int j = 0; j < 4; ++j) {                                      \
            f4 vA = pa[j];                                                 \
            f4 vB = pb[j];                                                 \
            d0 = fmaf(vA.x, wA[j].x, d0); d1 = fmaf(vA.x, wA[j].y, d1);    \
            d0 = fmaf(vA.y, wA[j].z, d0); d1 = fmaf(vA.y, wA[j].w, d1);    \
            d0 = fmaf(vA.z, wB[j].x, d0); d1 = fmaf(vA.z, wB[j].y, d1);    \
            d0 = fmaf(vA.w, wB[j].z, d0); d1 = fmaf(vA.w, wB[j].w, d1);    \
            d2 = fmaf(vB.x, wA[j].x, d2); d3 = fmaf(vB.x, wA[j].y, d3);    \
            d2 = fmaf(vB.y, wA[j].z, d2); d3 = fmaf(vB.y, wA[j].w, d3);    \
            d2 = fmaf(vB.z, wB[j].x, d2); d3 = fmaf(vB.z, wB[j].y, d3);    \
            d2 = fmaf(vB.w, wB[j].z, d2); d3 = fmaf(vB.w, wB[j].w, d3);    \
        }                                                                  \
    } while (0)

// Issue nontemporal loads of a row pair (rows `row`, `row+1`) into pa/pb.
#define PAIR_LOAD(pa, pb, row)                                             \
    do {                                                                   \
        const f4* __restrict__ xp = x4 + (size_t)(row) * 256;              \
        _Pragma("unroll")                                                  \
        for (int j = 0; j < 4; ++j) {                                      \
            const int f = lane + 64 * j;                                   \
            pa[j] = ld_nt(xp + f);                                         \
            pb[j] = ld_nt(xp + 256 + f);                                   \
        }                                                                  \
    } while (0)

__global__ __launch_bounds__(256) void qlayer_kernel(
    const float* __restrict__ x,    // [B,1024]
    const float* __restrict__ w,    // [1024,2] row-major: w[d*2+q]
    const float* __restrict__ bias, // [2]
    const float* __restrict__ wq,   // [2,2]
    float* __restrict__ out,        // [B,2]
    int B)
{
    const int lane = threadIdx.x & 63;
    const int wave = threadIdx.x >> 6;
    const int rowBase = (blockIdx.x * WAVES_PER_BLOCK + wave) * ROWS_PER_WAVE;
    if (rowBase >= B) return;

    // Preload this lane's weight fragments: lane handles float4-indices
    // f = lane + 64*j (j=0..3) of the 256-float4 row; w fragment for d=4f
    // is 8 consecutive floats = two float4 at indices 2f, 2f+1.
    const f4* __restrict__ w4 = (const f4*)w;
    f4 wA[4], wB[4];
#pragma unroll
    for (int j = 0; j < 4; ++j) {
        int f = lane + 64 * j;
        wA[j] = w4[2 * f];
        wB[j] = w4[2 * f + 1];
    }

    const float b0 = bias[0], b1 = bias[1];

    // Per-layer RX angle sin/cos (constant across rows)
    float cw[2][2], sw[2][2];
#pragma unroll
    for (int l = 0; l < 2; ++l) {
#pragma unroll
        for (int q = 0; q < 2; ++q) {
            float t = 0.5f * wq[l * 2 + q];
            __sincosf(t, &sw[l][q], &cw[l][q]);
        }
    }

    float2* __restrict__ out2 = (float2*)out;
    const f4* __restrict__ x4 = (const f4*)x;

    if (rowBase + ROWS_PER_WAVE <= B) {
        // ---- fast path: 8 rows = pairs P0..P3.  Ring buffers:
        //  X holds P0 then P2; Y holds P1 then P3. 16 loads in flight
        //  through each tail.
        f4 Xa[4], Xb[4], Ya[4], Yb[4];

        PAIR_LOAD(Xa, Xb, rowBase + 0);   // P0
        PAIR_LOAD(Ya, Yb, rowBase + 2);   // P1

        // ---- group 0: rows rowBase..rowBase+3 ----
        {
            float s0 = 0.f, s1 = 0.f, s2 = 0.f, s3 = 0.f;
            float s4 = 0.f, s5 = 0.f, s6 = 0.f, s7 = 0.f;

            PAIR_FMA(Xa, Xb, s0, s1, s2, s3);   // consumes P0
            PAIR_LOAD(Xa, Xb, rowBase + 4);     // issue P2
            PAIR_FMA(Ya, Yb, s4, s5, s6, s7);   // consumes P1
            PAIR_LOAD(Ya, Yb, rowBase + 6);     // issue P3

            // combined butterfly over 8 sums (6 serial steps, 8-way ILP)
#pragma unroll
            for (int off = 32; off >= 1; off >>= 1) {
                s0 += __shfl_xor(s0, off, 64);
                s1 += __shfl_xor(s1, off, 64);
                s2 += __shfl_xor(s2, off, 64);
                s3 += __shfl_xor(s3, off, 64);
                s4 += __shfl_xor(s4, off, 64);
                s5 += __shfl_xor(s5, off, 64);
                s6 += __shfl_xor(s6, off, 64);
                s7 += __shfl_xor(s7, off, 64);
            }

            // sums are lane-uniform now; lane k (k=lane&3) picks row k's h0,h1
            const int k = lane & 3;
            float h0 = (k & 1) ? s2 : s0;
            float h0h = (k & 1) ? s6 : s4;
            h0 = (k & 2) ? h0h : h0;
            float h1 = (k & 1) ? s3 : s1;
            float h1h = (k & 1) ? s7 : s5;
            h1 = (k & 2) ? h1h : h1;

            float2 z = run_circuit(h0 + b0, h1 + b1, cw, sw);
            if (lane < 4) out2[rowBase + lane] = z;
        }

        // ---- group 1: rows rowBase+4..rowBase+7 ----
        {
            float s0 = 0.f, s1 = 0.f, s2 = 0.f, s3 = 0.f;
            float s4 = 0.f, s5 = 0.f, s6 = 0.f, s7 = 0.f;

            PAIR_FMA(Xa, Xb, s0, s1, s2, s3);   // consumes P2
            PAIR_FMA(Ya, Yb, s4, s5, s6, s7);   // consumes P3

#pragma unroll
            for (int off = 32; off >= 1; off >>= 1) {
                s0 += __shfl_xor(s0, off, 64);
                s1 += __shfl_xor(s1, off, 64);
                s2 += __shfl_xor(s2, off, 64);
                s3 += __shfl_xor(s3, off, 64);
                s4 += __shfl_xor(s4, off, 64);
                s5 += __shfl_xor(s5, off, 64);
                s6 += __shfl_xor(s6, off, 64);
                s7 += __shfl_xor(s7, off, 64);
            }

            const int k = lane & 3;
            float h0 = (k & 1) ? s2 : s0;
            float h0h = (k & 1) ? s6 : s4;
            h0 = (k & 2) ? h0h : h0;
            float h1 = (k & 1) ? s3 : s1;
            float h1h = (k & 1) ? s7 : s5;
            h1 = (k & 2) ? h1h : h1;

            float2 z = run_circuit(h0 + b0, h1 + b1, cw, sw);
            if (lane < 4) out2[rowBase + 4 + lane] = z;
        }
    } else {
        // ---- tail path: guarded, non-pipelined (taken only if B % 32 != 0) ----
#pragma unroll
        for (int r = 0; r < ROWS_PER_WAVE; r += 2) {
            const int rowA = rowBase + r;
            if (rowA >= B) break;
            const int rowB = rowA + 1;
            const bool hasB = (rowB < B);

            const f4* __restrict__ xA = x4 + (size_t)rowA * 256;
            const f4* __restrict__ xB = x4 + (size_t)(hasB ? rowB : rowA) * 256;

            float a0 = 0.f, a1 = 0.f, c0s = 0.f, c1s = 0.f;
#pragma unroll
            for (int j = 0; j < 4; ++j) {
                const int f = lane + 64 * j;
                f4 vA = xA[f];
                f4 vB = xB[f];
                a0 = fmaf(vA.x, wA[j].x, a0); a1 = fmaf(vA.x, wA[j].y, a1);
                a0 = fmaf(vA.y, wA[j].z, a0); a1 = fmaf(vA.y, wA[j].w, a1);
                a0 = fmaf(vA.z, wB[j].x, a0); a1 = fmaf(vA.z, wB[j].y, a1);
                a0 = fmaf(vA.w, wB[j].z, a0); a1 = fmaf(vA.w, wB[j].w, a1);
                c0s = fmaf(vB.x, wA[j].x, c0s); c1s = fmaf(vB.x, wA[j].y, c1s);
                c0s = fmaf(vB.y, wA[j].z, c0s); c1s = fmaf(vB.y, wA[j].w, c1s);
                c0s = fmaf(vB.z, wB[j].x, c0s); c1s = fmaf(vB.z, wB[j].y, c1s);
                c0s = fmaf(vB.w, wB[j].z, c0s); c1s = fmaf(vB.w, wB[j].w, c1s);
            }

#pragma unroll
            for (int off = 32; off >= 1; off >>= 1) {
                a0  += __shfl_xor(a0, off, 64);
                a1  += __shfl_xor(a1, off, 64);
                c0s += __shfl_xor(c0s, off, 64);
                c1s += __shfl_xor(c1s, off, 64);
            }

            float2 zA = run_circuit(a0 + b0, a1 + b1, cw, sw);
            float2 zB = run_circuit(c0s + b0, c1s + b1, cw, sw);

            if (lane == 0) {
                out2[rowA] = zA;
                if (hasB) out2[rowB] = zB;
            }
        }
    }
}

extern "C" void kernel_launch(void* const* d_in, const int* in_sizes, int n_in,
                              void* d_out, int out_size, void* d_ws, size_t ws_size,
                              hipStream_t stream) {
    const float* x    = (const float*)d_in[0];
    const float* w    = (const float*)d_in[1];
    const float* bias = (const float*)d_in[2];
    const float* wq   = (const float*)d_in[3];
    float* out = (float*)d_out;

    const int B = in_sizes[0] / 1024;
    const int grid = (B + ROWS_PER_BLOCK - 1) / ROWS_PER_BLOCK;
    qlayer_kernel<<<grid, 256, 0, stream>>>(x, w, bias, wq, out, B);
}